// Round 4
// baseline (294.966 us; speedup 1.0000x reference)
//
#include <hip/hip_runtime.h>

// Problem constants (fixed by the reference)
constexpr int L    = 8192;   // vector_length
constexpr int B    = 4096;   // batch (columns)
constexpr int RANK = 8;

// Pass-1 tiling: grid = CB col-blocks x NCHUNK l-chunks
constexpr int CB      = 4;            // column blocks of 1024 cols (256 thr x float4)
constexpr int NCHUNK  = 128;          // l-chunks -> 512 blocks (round-2 winner geometry)
constexpr int LPC     = L / NCHUNK;   // 64 l-values per chunk
constexpr int COLS_PB = 1024;
constexpr int UNROLL  = 8;

// Pass-2 tiling
constexpr int LPB = 16;               // l-rows per block -> 2048 blocks

// ---------------------------------------------------------------------------
// pass1: T[r][b] += sum_{l in chunk} V[r][l] * in[l][b]   (device-scope atomics,
// replaces the partial-slab round-trip + separate reduce kernel)
// ---------------------------------------------------------------------------
__global__ __launch_bounds__(256) void lr_pass1(const float* __restrict__ in,
                                                const float* __restrict__ V,
                                                float* __restrict__ T) {
    const int cb  = blockIdx.x % CB;
    const int lc  = blockIdx.x / CB;
    const int col = cb * COLS_PB + threadIdx.x * 4;
    const int l0  = lc * LPC;

    __shared__ float vs[RANK][LPC];     // 2 KiB
    for (int i = threadIdx.x; i < RANK * LPC; i += 256) {
        const int r  = i / LPC;
        const int ll = i % LPC;
        vs[r][ll] = V[r * L + l0 + ll];
    }
    __syncthreads();

    float4 acc[RANK];
#pragma unroll
    for (int r = 0; r < RANK; ++r) acc[r] = make_float4(0.f, 0.f, 0.f, 0.f);

    const float* base = in + (size_t)l0 * B + col;
    for (int li = 0; li < LPC; li += UNROLL) {
        float4 x[UNROLL];
#pragma unroll
        for (int j = 0; j < UNROLL; ++j)
            x[j] = *(const float4*)(base + (size_t)(li + j) * B);
#pragma unroll
        for (int j = 0; j < UNROLL; ++j) {
#pragma unroll
            for (int r = 0; r < RANK; ++r) {
                const float v = vs[r][li + j];
                acc[r].x += v * x[j].x;
                acc[r].y += v * x[j].y;
                acc[r].z += v * x[j].z;
                acc[r].w += v * x[j].w;
            }
        }
    }

#pragma unroll
    for (int r = 0; r < RANK; ++r) {
        float* t = T + r * B + col;
        atomicAdd(t + 0, acc[r].x);
        atomicAdd(t + 1, acc[r].y);
        atomicAdd(t + 2, acc[r].z);
        atomicAdd(t + 3, acc[r].w);
    }
}

// ---------------------------------------------------------------------------
// pass2: out[l][b] = sum_r U[r][l] * T[r][b]
// ---------------------------------------------------------------------------
__global__ __launch_bounds__(256) void lr_pass2(const float* __restrict__ T,
                                                const float* __restrict__ U,
                                                float* __restrict__ out) {
    const int cb  = blockIdx.x % CB;
    const int lb  = blockIdx.x / CB;
    const int col = cb * COLS_PB + threadIdx.x * 4;
    const int l0  = lb * LPB;

    __shared__ float us[RANK][LPB];     // 512 B
    if (threadIdx.x < RANK * LPB) {
        const int r  = threadIdx.x / LPB;
        const int ll = threadIdx.x % LPB;
        us[r][ll] = U[r * L + l0 + ll];
    }
    __syncthreads();

    float4 t[RANK];
#pragma unroll
    for (int r = 0; r < RANK; ++r) t[r] = *(const float4*)(T + r * B + col);

#pragma unroll
    for (int li = 0; li < LPB; ++li) {
        float4 o = make_float4(0.f, 0.f, 0.f, 0.f);
#pragma unroll
        for (int r = 0; r < RANK; ++r) {
            const float u = us[r][li];
            o.x += u * t[r].x;
            o.y += u * t[r].y;
            o.z += u * t[r].z;
            o.w += u * t[r].w;
        }
        *(float4*)(out + (size_t)(l0 + li) * B + col) = o;
    }
}

// ---------------------------------------------------------------------------
extern "C" void kernel_launch(void* const* d_in, const int* in_sizes, int n_in,
                              void* d_out, int out_size, void* d_ws, size_t ws_size,
                              hipStream_t stream) {
    const float* in = (const float*)d_in[0];   // [L, B]
    const float* U  = (const float*)d_in[1];   // [RANK, L]
    const float* V  = (const float*)d_in[2];   // [RANK, L]
    float* out = (float*)d_out;                // [L, B]

    // ws layout: T (RANK*B floats = 128 KiB), zeroed every call (ws is
    // re-poisoned 0xAA before each timed launch)
    float* T = (float*)d_ws;
    hipMemsetAsync(T, 0, (size_t)RANK * B * sizeof(float), stream);

    lr_pass1<<<CB * NCHUNK,    256, 0, stream>>>(in, V, T);
    lr_pass2<<<CB * (L / LPB), 256, 0, stream>>>(T, U, out);
}